// Round 4
// baseline (75.869 us; speedup 1.0000x reference)
//
#include <hip/hip_runtime.h>
#include <math.h>

#define NROWS 2048
#define DIMS  512
#define KG    5
#define BM    128
#define BKF   64
#define ACTIVE_BLOCKS 528   // 136 (XX tri) + 136 (YY tri) + 256 (XY full)

// invc[k] = 1/(2*gamma^2), gammas = {2,1,0.5,0.25,0.125}
__device__ __constant__ float c_invc[KG] = {0.125f, 0.5f, 2.0f, 8.0f, 32.0f};

typedef __attribute__((ext_vector_type(8))) short bf16x8;
typedef __attribute__((ext_vector_type(4))) float f32x4;

__device__ __forceinline__ unsigned short f2bf(float x) {
    unsigned int u = __float_as_uint(x);
    unsigned int r = (u + 0x7fffu + ((u >> 16) & 1u)) >> 16;
    return (unsigned short)r;
}

__device__ __forceinline__ void gload_lds16(const void* g, void* l) {
    __builtin_amdgcn_global_load_lds(
        (const __attribute__((address_space(1))) unsigned int*)g,
        (__attribute__((address_space(3))) unsigned int*)l, 16, 0, 0);
}

// ============ prep: convert f32->bf16 + row norms + h pairs + zero accumulators ============
// 256 blocks x 256 threads; one wave per pair j: rows {2j,2j+1} of BOTH Xs and Xt.
__global__ void prep_kernel(const float* __restrict__ Xs, const float* __restrict__ Xt,
                            unsigned short* __restrict__ Xsb, unsigned short* __restrict__ Xtb,
                            float* __restrict__ ns, float* __restrict__ nt,
                            float* __restrict__ h, double* __restrict__ sums,
                            int* __restrict__ counter) {
    if (blockIdx.x == 0) {
        if (threadIdx.x < 16) sums[threadIdx.x] = 0.0;
        if (threadIdx.x == 16) *counter = 0;
    }

    const int pairI = blockIdx.x * 4 + (threadIdx.x >> 6);   // 0..1023
    const int lane = threadIdx.x & 63;
    const int i = 2 * pairI, j = i + 1;

    const float* psi = Xs + (size_t)i * DIMS + lane * 8;
    const float* psj = Xs + (size_t)j * DIMS + lane * 8;
    const float* pti = Xt + (size_t)i * DIMS + lane * 8;
    const float* ptj = Xt + (size_t)j * DIMS + lane * 8;
    const float4 a0 = *(const float4*)psi, a1 = *(const float4*)(psi + 4);
    const float4 b0 = *(const float4*)psj, b1 = *(const float4*)(psj + 4);
    const float4 c0 = *(const float4*)pti, c1 = *(const float4*)(pti + 4);
    const float4 d0 = *(const float4*)ptj, d1 = *(const float4*)(ptj + 4);

#define DOT8(u0, u1, v0, v1) (u0.x*v0.x + u0.y*v0.y + u0.z*v0.z + u0.w*v0.w + \
                              u1.x*v1.x + u1.y*v1.y + u1.z*v1.z + u1.w*v1.w)
    float r[8];
    r[0] = DOT8(a0, a1, a0, a1);   // |xs_i|^2
    r[1] = DOT8(b0, b1, b0, b1);   // |xs_j|^2
    r[2] = DOT8(c0, c1, c0, c1);   // |xt_i|^2
    r[3] = DOT8(d0, d1, d0, d1);   // |xt_j|^2
    r[4] = DOT8(a0, a1, b0, b1);   // xs_i . xs_j
    r[5] = DOT8(c0, c1, d0, d1);   // xt_i . xt_j
    r[6] = DOT8(a0, a1, d0, d1);   // xs_i . xt_j  (XY)
    r[7] = DOT8(c0, c1, b0, b1);   // xt_i . xs_j  (YX)
#undef DOT8

    // bf16 stores (16 B/lane, coalesced)
    {
        bf16x8 o;
        o[0]=(short)f2bf(a0.x); o[1]=(short)f2bf(a0.y); o[2]=(short)f2bf(a0.z); o[3]=(short)f2bf(a0.w);
        o[4]=(short)f2bf(a1.x); o[5]=(short)f2bf(a1.y); o[6]=(short)f2bf(a1.z); o[7]=(short)f2bf(a1.w);
        *(bf16x8*)(Xsb + (size_t)i * DIMS + lane * 8) = o;
        o[0]=(short)f2bf(b0.x); o[1]=(short)f2bf(b0.y); o[2]=(short)f2bf(b0.z); o[3]=(short)f2bf(b0.w);
        o[4]=(short)f2bf(b1.x); o[5]=(short)f2bf(b1.y); o[6]=(short)f2bf(b1.z); o[7]=(short)f2bf(b1.w);
        *(bf16x8*)(Xsb + (size_t)j * DIMS + lane * 8) = o;
        o[0]=(short)f2bf(c0.x); o[1]=(short)f2bf(c0.y); o[2]=(short)f2bf(c0.z); o[3]=(short)f2bf(c0.w);
        o[4]=(short)f2bf(c1.x); o[5]=(short)f2bf(c1.y); o[6]=(short)f2bf(c1.z); o[7]=(short)f2bf(c1.w);
        *(bf16x8*)(Xtb + (size_t)i * DIMS + lane * 8) = o;
        o[0]=(short)f2bf(d0.x); o[1]=(short)f2bf(d0.y); o[2]=(short)f2bf(d0.z); o[3]=(short)f2bf(d0.w);
        o[4]=(short)f2bf(d1.x); o[5]=(short)f2bf(d1.y); o[6]=(short)f2bf(d1.z); o[7]=(short)f2bf(d1.w);
        *(bf16x8*)(Xtb + (size_t)j * DIMS + lane * 8) = o;
    }

#pragma unroll
    for (int v = 0; v < 8; ++v)
        for (int off = 32; off > 0; off >>= 1) r[v] += __shfl_down(r[v], off, 64);

    if (lane == 0) {
        ns[i] = r[0]; ns[j] = r[1]; nt[i] = r[2]; nt[j] = r[3];
#pragma unroll
        for (int g = 0; g < KG; ++g) {
            const float ic = c_invc[g];
            h[g * 1024 + pairI] = __expf(-(r[0] + r[1] - 2.f * r[4]) * ic)
                                + __expf(-(r[2] + r[3] - 2.f * r[5]) * ic)
                                - __expf(-(r[0] + r[3] - 2.f * r[6]) * ic)
                                - __expf(-(r[2] + r[1] - 2.f * r[7]) * ic);
        }
    }
}

// ============ gram (2-phase prefetch) + exp-reduce + last-block finalize ============
// pair z: 0 = XX (upper tri, x2, diag analytic), 1 = YY (same), 2 = XY (full)
// LDS: row r = 128 B (8 chunks of 16 B); chunk c at slot c^(r&7); pre-swizzled global src.
__global__ __launch_bounds__(256) void gram_fused_kernel(const unsigned short* __restrict__ Xsb,
                                                         const unsigned short* __restrict__ Xtb,
                                                         const float* __restrict__ ns,
                                                         const float* __restrict__ nt,
                                                         const float* __restrict__ h,
                                                         double* __restrict__ sums,
                                                         int* __restrict__ counter,
                                                         float* __restrict__ out) {
    const int pair = blockIdx.z;
    const int bx = blockIdx.x, by = blockIdx.y;
    if (pair < 2 && bx < by) return;   // inactive blocks exit before any sync/atomic

    const unsigned short* A = (pair == 1) ? Xtb : Xsb;
    const unsigned short* B = (pair == 0) ? Xsb : Xtb;
    const float* na = (pair == 1) ? nt : ns;
    const float* nb = (pair == 0) ? ns : nt;
    const int row0 = by * BM, col0 = bx * BM;

    __shared__ unsigned short Asm[2][BM * BKF];   // 2 x 16 KB
    __shared__ unsigned short Bsm[2][BM * BKF];   // 2 x 16 KB
    __shared__ float redf[KG][4];
    __shared__ int lastS;
    // finalize scratch
    __shared__ float h4[KG][512];
    __shared__ float hsumS[KG];
    __shared__ float qdotS[15];
    __shared__ double sumsS[16];

    const int tid = threadIdx.x;
    const int lane = tid & 63;
    const int w = tid >> 6;
    const int wr = w >> 1, wc = w & 1;            // 2x2 wave grid, 64x64 per wave

    f32x4 acc[4][4] = {};

    const int lrow8  = lane >> 3;                 // row within 8-row stripe
    const int lchunk = (lane & 7) ^ lrow8;        // pre-swizzled source chunk

#define STAGE(buf, kt)                                                                  \
    {                                                                                   \
        _Pragma("unroll")                                                               \
        for (int q = 0; q < 4; ++q) {                                                   \
            const int r0 = w * 32 + q * 8;                                              \
            const int row = r0 + lrow8;                                                 \
            gload_lds16(A + (size_t)(row0 + row) * DIMS + (kt) + lchunk * 8,            \
                        &Asm[buf][r0 * 64]);                                            \
            gload_lds16(B + (size_t)(col0 + row) * DIMS + (kt) + lchunk * 8,            \
                        &Bsm[buf][r0 * 64]);                                            \
        }                                                                               \
    }

    STAGE(0, 0);
    __syncthreads();

    const int h16 = lane >> 4;
#pragma unroll
    for (int t = 0; t < 8; ++t) {
        const int cur = t & 1;
        if (t < 7) STAGE(cur ^ 1, (t + 1) * BKF);

        bf16x8 af[2][4], bv[2][4];
#pragma unroll
        for (int kk = 0; kk < 2; ++kk)
#pragma unroll
            for (int m = 0; m < 4; ++m) {
                const int ra = wr * 64 + m * 16 + (lane & 15);
                af[kk][m] = *(const bf16x8*)((const char*)Asm[cur] + ra * 128 + (((kk * 4 + h16) ^ (ra & 7)) * 16));
                const int rb = wc * 64 + m * 16 + (lane & 15);
                bv[kk][m] = *(const bf16x8*)((const char*)Bsm[cur] + rb * 128 + (((kk * 4 + h16) ^ (rb & 7)) * 16));
            }
#pragma unroll
        for (int m = 0; m < 4; ++m)
#pragma unroll
            for (int n = 0; n < 4; ++n) {
                acc[m][n] = __builtin_amdgcn_mfma_f32_16x16x32_bf16(af[0][m], bv[0][n], acc[m][n], 0, 0, 0);
                acc[m][n] = __builtin_amdgcn_mfma_f32_16x16x32_bf16(af[1][m], bv[1][n], acc[m][n], 0, 0, 0);
            }
        __syncthreads();   // drains vmcnt (prefetch) + lgkmcnt; one barrier per K-step
    }
#undef STAGE

    // epilogue: C/D layout col = lane&15, row = (lane>>4)*4 + reg
    float lsum[KG] = {0.f, 0.f, 0.f, 0.f, 0.f};
    const int gcol0 = col0 + wc * 64 + (lane & 15);
    const int grow0 = row0 + wr * 64 + (lane >> 4) * 4;
    const bool diagTile = (pair < 2) && (bx == by);

    float colnorm[4];
#pragma unroll
    for (int n = 0; n < 4; ++n) colnorm[n] = nb[gcol0 + n * 16];

#pragma unroll
    for (int m = 0; m < 4; ++m) {
        const float4 rn4 = *(const float4*)&na[grow0 + m * 16];
        const float rn[4] = {rn4.x, rn4.y, rn4.z, rn4.w};
#pragma unroll
        for (int jj = 0; jj < 4; ++jj) {
            const int grow = grow0 + m * 16 + jj;
#pragma unroll
            for (int n = 0; n < 4; ++n) {
                const int gcol = gcol0 + n * 16;
                const float d = rn[jj] + colnorm[n] - 2.f * acc[m][n][jj];
                if (pair == 2) {
#pragma unroll
                    for (int g = 0; g < KG; ++g) lsum[g] += __expf(-d * c_invc[g]);
                } else if (!diagTile) {
#pragma unroll
                    for (int g = 0; g < KG; ++g) lsum[g] += 2.f * __expf(-d * c_invc[g]);
                } else {
                    if (gcol == grow) {
#pragma unroll
                        for (int g = 0; g < KG; ++g) lsum[g] += 1.f;   // exp(0) exactly
                    } else if (gcol > grow) {
#pragma unroll
                        for (int g = 0; g < KG; ++g) lsum[g] += 2.f * __expf(-d * c_invc[g]);
                    }
                }
            }
        }
    }

#pragma unroll
    for (int g = 0; g < KG; ++g) {
        float v = lsum[g];
        for (int off = 32; off > 0; off >>= 1) v += __shfl_down(v, off, 64);
        if (lane == 0) redf[g][w] = v;
    }
    __syncthreads();
    if (tid < KG) {
        const double s = (double)redf[tid][0] + (double)redf[tid][1] +
                         (double)redf[tid][2] + (double)redf[tid][3];
        atomicAdd(&sums[pair * KG + tid], s);
    }
    __syncthreads();   // all waves drained (vmcnt) -> atomics complete at coherent point

    if (tid == 0) {
        __threadfence();
        lastS = (atomicAdd(counter, 1) == ACTIVE_BLOCKS - 1);
    }
    __syncthreads();
    if (!lastS) return;

    // ================= finalize (last active block only) =================
    const int t = tid;
    const int wv = t >> 6, ln = t & 63;

    if (t < 16) sumsS[t] = atomicAdd(&sums[t], 0.0);   // coherent RMW read
    for (int k = 0; k < KG; ++k)
        for (int j2 = t; j2 < 512; j2 += 256)
            h4[k][j2] = h[k * 1024 + 2 * j2] - h[k * 1024 + 2 * j2 + 1];

    {
        float s[KG] = {0.f, 0.f, 0.f, 0.f, 0.f};
        for (int j = t; j < 1024; j += 256)
#pragma unroll
            for (int k = 0; k < KG; ++k) s[k] += h[k * 1024 + j];
#pragma unroll
        for (int k = 0; k < KG; ++k) {
            float v = s[k];
            for (int off = 32; off > 0; off >>= 1) v += __shfl_down(v, off, 64);
            if (ln == 0) redf[k][wv] = v;
        }
    }
    __syncthreads();
    if (t < KG) hsumS[t] = redf[t][0] + redf[t][1] + redf[t][2] + redf[t][3];
    __syncthreads();

    const int pa[15] = {0,0,0,0,0,1,1,1,1,2,2,2,3,3,4};
    const int pb[15] = {0,1,2,3,4,1,2,3,4,2,3,4,3,4,4};
    for (int pi = wv; pi < 15; pi += 4) {
        float s = 0.f;
        for (int j = ln; j < 512; j += 64) s += h4[pa[pi]][j] * h4[pb[pi]][j];
        for (int off = 32; off > 0; off >>= 1) s += __shfl_down(s, off, 64);
        if (ln == 0) qdotS[pi] = s;
    }
    __syncthreads();

    if (t < 64) {
        const double n = 2048.0;
        double Q[KG][KG], p[KG], eta[KG];
        {
            int idx = 0;
            double dd[KG][KG];
#pragma unroll
            for (int a = 0; a < KG; ++a)
#pragma unroll
                for (int b = a; b < KG; ++b) { dd[a][b] = qdotS[idx]; dd[b][a] = qdotS[idx]; ++idx; }
#pragma unroll
            for (int a = 0; a < KG; ++a)
#pragma unroll
                for (int b = 0; b < KG; ++b) {
                    double qp = (4.0 / n) * (dd[a][b] + ((a == b) ? dd[a][a] : 0.0));
                    Q[a][b] = 2.0 * qp + ((a == b) ? 1e-5 : 0.0);
                }
        }
#pragma unroll
        for (int k = 0; k < KG; ++k) {
            p[k] = -2.0 * (double)hsumS[k] / n;
            eta[k] = (sumsS[k] + sumsS[KG + k] - 2.0 * sumsS[2 * KG + k]) / (n * n);
        }

        const int mask = t;
        const bool valid = (mask >= 1 && mask < 32);
        double beta[KG] = {0, 0, 0, 0, 0};
        double obj = INFINITY;

        if (valid) {
            double m[KG];
#pragma unroll
            for (int k = 0; k < KG; ++k) m[k] = (mask >> k) & 1 ? 1.0 : 0.0;
            double M[6][7];
#pragma unroll
            for (int a = 0; a < 6; ++a)
#pragma unroll
                for (int b = 0; b < 7; ++b) M[a][b] = 0.0;
#pragma unroll
            for (int a = 0; a < KG; ++a) {
#pragma unroll
                for (int b = 0; b < KG; ++b) M[a][b] = m[a] * Q[a][b] * m[b];
                M[a][a] += 1.0 - m[a];
                M[a][KG] = m[a];
                M[KG][a] = m[a];
                M[a][6] = -m[a] * p[a];
            }
            M[KG][6] = 1.0;
#pragma unroll
            for (int col = 0; col < 6; ++col) {
                const double dinv = 1.0 / M[col][col];
#pragma unroll
                for (int rr = 0; rr < 6; ++rr) {
                    if (rr > col) {
                        const double f = M[rr][col] * dinv;
#pragma unroll
                        for (int c = 0; c < 7; ++c)
                            if (c >= col) M[rr][c] -= f * M[col][c];
                    }
                }
            }
            double sol[6];
#pragma unroll
            for (int rr = 5; rr >= 0; --rr) {
                double s = M[rr][6];
#pragma unroll
                for (int c = 0; c < 6; ++c)
                    if (c > rr) s -= M[rr][c] * sol[c];
                sol[rr] = s / M[rr][rr];
            }
#pragma unroll
            for (int k = 0; k < KG; ++k) beta[k] = sol[k] * m[k];
            double o = 0.0;
#pragma unroll
            for (int a = 0; a < KG; ++a) {
                double qb = 0.0;
#pragma unroll
                for (int b = 0; b < KG; ++b) qb += Q[a][b] * beta[b];
                o += 0.5 * beta[a] * qb + p[a] * beta[a];
            }
            bool feas = true;
#pragma unroll
            for (int k = 0; k < KG; ++k) if (!(beta[k] >= -1e-7)) feas = false;
            obj = feas ? o : INFINITY;
        }

        double bobj = obj;
        int blane = valid ? mask : 9999;
        for (int off = 32; off > 0; off >>= 1) {
            const double o2 = __shfl_down(bobj, off, 64);
            const int l2 = __shfl_down(blane, off, 64);
            if (o2 < bobj || (o2 == bobj && l2 < blane)) { bobj = o2; blane = l2; }
        }
        bobj = __shfl(bobj, 0, 64);
        blane = __shfl(blane, 0, 64);
        if (bobj > 1e300) blane = 1;

        if (mask == blane) {
            double o = 0.0;
#pragma unroll
            for (int k = 0; k < KG; ++k) o += eta[k] * beta[k];
            out[0] = (float)o;
        }
    }
}

// ---------------- launch ----------------
extern "C" void kernel_launch(void* const* d_in, const int* in_sizes, int n_in,
                              void* d_out, int out_size, void* d_ws, size_t ws_size,
                              hipStream_t stream) {
    const float* Xs = (const float*)d_in[0];
    const float* Xt = (const float*)d_in[1];
    float* out = (float*)d_out;

    char* ws = (char*)d_ws;
    double* sums   = (double*)ws;                              // 16 doubles (128 B)
    int*    counter = (int*)(ws + 128);                        // reserve 128 B
    float*  ns = (float*)(ws + 256);                           // 2048 f32
    float*  nt = (float*)(ws + 256 + 8192);                    // 2048 f32
    float*  h  = (float*)(ws + 256 + 16384);                   // 5*1024 f32
    unsigned short* Xsb = (unsigned short*)(ws + 40960);            // 2 MB bf16
    unsigned short* Xtb = (unsigned short*)(ws + 40960 + 2097152);  // 2 MB bf16

    prep_kernel<<<256, 256, 0, stream>>>(Xs, Xt, Xsb, Xtb, ns, nt, h, sums, counter);
    gram_fused_kernel<<<dim3(16, 16, 3), 256, 0, stream>>>(Xsb, Xtb, ns, nt, h, sums, counter, out);
}

// Round 5
// 60.570 us; speedup vs baseline: 1.2526x; 1.2526x over previous
//
#include <hip/hip_runtime.h>
#include <math.h>

#define NROWS 2048
#define DIMS  512
#define KG    5
#define BM    64
#define BKF   64

// invc[k] = 1/(2*gamma^2), gammas = {2,1,0.5,0.25,0.125} -> {0.125,0.5,2,8,32} (x4 chain)
__device__ __constant__ float c_invc[KG] = {0.125f, 0.5f, 2.0f, 8.0f, 32.0f};

typedef __attribute__((ext_vector_type(8))) short bf16x8;
typedef __attribute__((ext_vector_type(4))) float f32x4;

__device__ __forceinline__ unsigned short f2bf(float x) {
    unsigned int u = __float_as_uint(x);
    unsigned int r = (u + 0x7fffu + ((u >> 16) & 1u)) >> 16;
    return (unsigned short)r;
}

__device__ __forceinline__ void gload_lds16(const void* g, void* l) {
    __builtin_amdgcn_global_load_lds(
        (const __attribute__((address_space(1))) unsigned int*)g,
        (__attribute__((address_space(3))) unsigned int*)l, 16, 0, 0);
}

// ============ prep: convert f32->bf16 + row norms + h pairs + zero accumulators ============
// 256 blocks x 256 threads; one wave per pair j: rows {2j,2j+1} of BOTH Xs and Xt.
__global__ void prep_kernel(const float* __restrict__ Xs, const float* __restrict__ Xt,
                            unsigned short* __restrict__ Xsb, unsigned short* __restrict__ Xtb,
                            float* __restrict__ ns, float* __restrict__ nt,
                            float* __restrict__ h, double* __restrict__ sums) {
    if (blockIdx.x == 0 && threadIdx.x < 16) sums[threadIdx.x] = 0.0;

    const int pairI = blockIdx.x * 4 + (threadIdx.x >> 6);   // 0..1023
    const int lane = threadIdx.x & 63;
    const int i = 2 * pairI, j = i + 1;

    const float* psi = Xs + (size_t)i * DIMS + lane * 8;
    const float* psj = Xs + (size_t)j * DIMS + lane * 8;
    const float* pti = Xt + (size_t)i * DIMS + lane * 8;
    const float* ptj = Xt + (size_t)j * DIMS + lane * 8;
    const float4 a0 = *(const float4*)psi, a1 = *(const float4*)(psi + 4);
    const float4 b0 = *(const float4*)psj, b1 = *(const float4*)(psj + 4);
    const float4 c0 = *(const float4*)pti, c1 = *(const float4*)(pti + 4);
    const float4 d0 = *(const float4*)ptj, d1 = *(const float4*)(ptj + 4);

#define DOT8(u0, u1, v0, v1) (u0.x*v0.x + u0.y*v0.y + u0.z*v0.z + u0.w*v0.w + \
                              u1.x*v1.x + u1.y*v1.y + u1.z*v1.z + u1.w*v1.w)
    float r[8];
    r[0] = DOT8(a0, a1, a0, a1);   // |xs_i|^2
    r[1] = DOT8(b0, b1, b0, b1);   // |xs_j|^2
    r[2] = DOT8(c0, c1, c0, c1);   // |xt_i|^2
    r[3] = DOT8(d0, d1, d0, d1);   // |xt_j|^2
    r[4] = DOT8(a0, a1, b0, b1);   // xs_i . xs_j
    r[5] = DOT8(c0, c1, d0, d1);   // xt_i . xt_j
    r[6] = DOT8(a0, a1, d0, d1);   // xs_i . xt_j
    r[7] = DOT8(c0, c1, b0, b1);   // xt_i . xs_j
#undef DOT8

    {
        bf16x8 o;
        o[0]=(short)f2bf(a0.x); o[1]=(short)f2bf(a0.y); o[2]=(short)f2bf(a0.z); o[3]=(short)f2bf(a0.w);
        o[4]=(short)f2bf(a1.x); o[5]=(short)f2bf(a1.y); o[6]=(short)f2bf(a1.z); o[7]=(short)f2bf(a1.w);
        *(bf16x8*)(Xsb + (size_t)i * DIMS + lane * 8) = o;
        o[0]=(short)f2bf(b0.x); o[1]=(short)f2bf(b0.y); o[2]=(short)f2bf(b0.z); o[3]=(short)f2bf(b0.w);
        o[4]=(short)f2bf(b1.x); o[5]=(short)f2bf(b1.y); o[6]=(short)f2bf(b1.z); o[7]=(short)f2bf(b1.w);
        *(bf16x8*)(Xsb + (size_t)j * DIMS + lane * 8) = o;
        o[0]=(short)f2bf(c0.x); o[1]=(short)f2bf(c0.y); o[2]=(short)f2bf(c0.z); o[3]=(short)f2bf(c0.w);
        o[4]=(short)f2bf(c1.x); o[5]=(short)f2bf(c1.y); o[6]=(short)f2bf(c1.z); o[7]=(short)f2bf(c1.w);
        *(bf16x8*)(Xtb + (size_t)i * DIMS + lane * 8) = o;
        o[0]=(short)f2bf(d0.x); o[1]=(short)f2bf(d0.y); o[2]=(short)f2bf(d0.z); o[3]=(short)f2bf(d0.w);
        o[4]=(short)f2bf(d1.x); o[5]=(short)f2bf(d1.y); o[6]=(short)f2bf(d1.z); o[7]=(short)f2bf(d1.w);
        *(bf16x8*)(Xtb + (size_t)j * DIMS + lane * 8) = o;
    }

#pragma unroll
    for (int v = 0; v < 8; ++v)
        for (int off = 32; off > 0; off >>= 1) r[v] += __shfl_down(r[v], off, 64);

    if (lane == 0) {
        ns[i] = r[0]; ns[j] = r[1]; nt[i] = r[2]; nt[j] = r[3];
#pragma unroll
        for (int g = 0; g < KG; ++g) {
            const float ic = c_invc[g];
            h[g * 1024 + pairI] = __expf(-(r[0] + r[1] - 2.f * r[4]) * ic)
                                + __expf(-(r[2] + r[3] - 2.f * r[5]) * ic)
                                - __expf(-(r[0] + r[3] - 2.f * r[6]) * ic)
                                - __expf(-(r[2] + r[1] - 2.f * r[7]) * ic);
        }
    }
}

// ============ gram: 64x64 tiles, 4 waves (2x2 of 32x32), BK=64 double-buffered ============
// pair z: 0 = XX (upper tri, x2, diag analytic), 1 = YY (same), 2 = XY (full)
// LDS: row = 128 B (8 chunks of 16 B); chunk c at slot c^(r&7); pre-swizzled global src.
__global__ __launch_bounds__(256, 4) void gram_kernel(const unsigned short* __restrict__ Xsb,
                                                      const unsigned short* __restrict__ Xtb,
                                                      const float* __restrict__ ns,
                                                      const float* __restrict__ nt,
                                                      double* __restrict__ sums) {
    const int pair = blockIdx.z;
    const int bx = blockIdx.x, by = blockIdx.y;
    if (pair < 2 && bx < by) return;   // triangular grids for XX/YY

    const unsigned short* A = (pair == 1) ? Xtb : Xsb;
    const unsigned short* B = (pair == 0) ? Xsb : Xtb;
    const float* na = (pair == 1) ? nt : ns;
    const float* nb = (pair == 0) ? ns : nt;
    const int row0 = by * BM, col0 = bx * BM;

    __shared__ unsigned short Asm[2][BM * BKF];   // 2 x 8 KB
    __shared__ unsigned short Bsm[2][BM * BKF];   // 2 x 8 KB
    __shared__ float redf[KG][4];

    const int tid = threadIdx.x;
    const int lane = tid & 63;
    const int w = tid >> 6;
    const int wr = w >> 1, wc = w & 1;            // 2x2 wave grid, 32x32 per wave

    f32x4 acc[2][2] = {};

    const int lrow8  = lane >> 3;                 // row within 8-row stripe
    const int lchunk = (lane & 7) ^ lrow8;        // pre-swizzled source chunk
    const int h16 = lane >> 4;

#define STAGE(buf, kt)                                                                  \
    {                                                                                   \
        _Pragma("unroll")                                                               \
        for (int q = 0; q < 2; ++q) {                                                   \
            const int r0 = q * 32 + w * 8;                                              \
            const int row = r0 + lrow8;                                                 \
            gload_lds16(A + (size_t)(row0 + row) * DIMS + (kt) + lchunk * 8,            \
                        &Asm[buf][r0 * 64]);                                            \
            gload_lds16(B + (size_t)(col0 + row) * DIMS + (kt) + lchunk * 8,            \
                        &Bsm[buf][r0 * 64]);                                            \
        }                                                                               \
    }

    STAGE(0, 0);
    __syncthreads();

#pragma unroll
    for (int t = 0; t < 8; ++t) {
        const int cur = t & 1;
        if (t < 7) STAGE(cur ^ 1, (t + 1) * BKF);

        bf16x8 af[2][2], bv[2][2];
#pragma unroll
        for (int kk = 0; kk < 2; ++kk)
#pragma unroll
            for (int m = 0; m < 2; ++m) {
                const int ra = wr * 32 + m * 16 + (lane & 15);
                af[kk][m] = *(const bf16x8*)((const char*)Asm[cur] + ra * 128 + (((kk * 4 + h16) ^ (ra & 7)) * 16));
                const int rb = wc * 32 + m * 16 + (lane & 15);
                bv[kk][m] = *(const bf16x8*)((const char*)Bsm[cur] + rb * 128 + (((kk * 4 + h16) ^ (rb & 7)) * 16));
            }
#pragma unroll
        for (int m = 0; m < 2; ++m)
#pragma unroll
            for (int n = 0; n < 2; ++n) {
                acc[m][n] = __builtin_amdgcn_mfma_f32_16x16x32_bf16(af[0][m], bv[0][n], acc[m][n], 0, 0, 0);
                acc[m][n] = __builtin_amdgcn_mfma_f32_16x16x32_bf16(af[1][m], bv[1][n], acc[m][n], 0, 0, 0);
            }
        __syncthreads();
    }
#undef STAGE

    // epilogue: C/D layout col = lane&15, row = (lane>>4)*4 + reg
    // gamma power-chain: invc ratios are exactly 4x -> e_{g+1} = (e_g^2)^2
    float lsum[KG] = {0.f, 0.f, 0.f, 0.f, 0.f};
    const int gcol0 = col0 + wc * 32 + (lane & 15);
    const int grow0 = row0 + wr * 32 + (lane >> 4) * 4;
    const bool diagTile = (pair < 2) && (bx == by);
    const float wgt = (pair == 2) ? 1.f : 2.f;

    float colnorm[2];
#pragma unroll
    for (int n = 0; n < 2; ++n) colnorm[n] = nb[gcol0 + n * 16];

#pragma unroll
    for (int m = 0; m < 2; ++m) {
        const float4 rn4 = *(const float4*)&na[grow0 + m * 16];
        const float rn[4] = {rn4.x, rn4.y, rn4.z, rn4.w};
#pragma unroll
        for (int jj = 0; jj < 4; ++jj) {
            const int grow = grow0 + m * 16 + jj;
#pragma unroll
            for (int n = 0; n < 2; ++n) {
                const int gcol = gcol0 + n * 16;
                const float d = rn[jj] + colnorm[n] - 2.f * acc[m][n][jj];
                if (diagTile && gcol == grow) {
#pragma unroll
                    for (int g = 0; g < KG; ++g) lsum[g] += 1.f;      // exp(0) exactly
                } else if (!diagTile || gcol > grow) {
                    float e = __expf(-d * 0.125f);                    // gamma=2
#pragma unroll
                    for (int g = 0; g < KG; ++g) {
                        lsum[g] += wgt * e;
                        const float e2 = e * e;
                        e = e2 * e2;                                  // next gamma
                    }
                }
            }
        }
    }

#pragma unroll
    for (int g = 0; g < KG; ++g) {
        float v = lsum[g];
        for (int off = 32; off > 0; off >>= 1) v += __shfl_down(v, off, 64);
        if (lane == 0) redf[g][w] = v;
    }
    __syncthreads();
    if (tid < KG) {
        const double s = (double)redf[tid][0] + (double)redf[tid][1] +
                         (double)redf[tid][2] + (double)redf[tid][3];
        atomicAdd(&sums[pair * KG + tid], s);
    }
}

// ---------------- finalize: eta, Q, parallel QP over 31 masks ----------------
__global__ void finalize_kernel(const double* __restrict__ sums,
                                const float* __restrict__ h,
                                float* __restrict__ out) {
    __shared__ float h4[KG][512];
    __shared__ float hsumS[KG];
    __shared__ float qdotS[15];
    __shared__ float redh[KG][4];
    const int t = threadIdx.x;
    const int wv = t >> 6, ln = t & 63;

    for (int k = 0; k < KG; ++k)
        for (int j2 = t; j2 < 512; j2 += 256)
            h4[k][j2] = h[k * 1024 + 2 * j2] - h[k * 1024 + 2 * j2 + 1];

    {
        float s[KG] = {0.f, 0.f, 0.f, 0.f, 0.f};
        for (int j = t; j < 1024; j += 256)
#pragma unroll
            for (int k = 0; k < KG; ++k) s[k] += h[k * 1024 + j];
#pragma unroll
        for (int k = 0; k < KG; ++k) {
            float v = s[k];
            for (int off = 32; off > 0; off >>= 1) v += __shfl_down(v, off, 64);
            if (ln == 0) redh[k][wv] = v;
        }
    }
    __syncthreads();
    if (t < KG) hsumS[t] = redh[t][0] + redh[t][1] + redh[t][2] + redh[t][3];
    __syncthreads();

    const int pa[15] = {0,0,0,0,0,1,1,1,1,2,2,2,3,3,4};
    const int pb[15] = {0,1,2,3,4,1,2,3,4,2,3,4,3,4,4};
    for (int pi = wv; pi < 15; pi += 4) {
        float s = 0.f;
        for (int j = ln; j < 512; j += 64) s += h4[pa[pi]][j] * h4[pb[pi]][j];
        for (int off = 32; off > 0; off >>= 1) s += __shfl_down(s, off, 64);
        if (ln == 0) qdotS[pi] = s;
    }
    __syncthreads();

    // ---- parallel QP: lane = mask (1..31 valid), wave 0 only ----
    if (t < 64) {
        const double n = 2048.0;
        double Q[KG][KG], p[KG], eta[KG];
        {
            int idx = 0;
            double dd[KG][KG];
#pragma unroll
            for (int a = 0; a < KG; ++a)
#pragma unroll
                for (int b = a; b < KG; ++b) { dd[a][b] = qdotS[idx]; dd[b][a] = qdotS[idx]; ++idx; }
#pragma unroll
            for (int a = 0; a < KG; ++a)
#pragma unroll
                for (int b = 0; b < KG; ++b) {
                    double qp = (4.0 / n) * (dd[a][b] + ((a == b) ? dd[a][a] : 0.0));
                    Q[a][b] = 2.0 * qp + ((a == b) ? 1e-5 : 0.0);
                }
        }
#pragma unroll
        for (int k = 0; k < KG; ++k) {
            p[k] = -2.0 * (double)hsumS[k] / n;
            eta[k] = (sums[k] + sums[KG + k] - 2.0 * sums[2 * KG + k]) / (n * n);
        }

        const int mask = t;
        const bool valid = (mask >= 1 && mask < 32);
        double beta[KG] = {0, 0, 0, 0, 0};
        double obj = INFINITY;

        if (valid) {
            double m[KG];
#pragma unroll
            for (int k = 0; k < KG; ++k) m[k] = (mask >> k) & 1 ? 1.0 : 0.0;
            double M[6][7];
#pragma unroll
            for (int a = 0; a < 6; ++a)
#pragma unroll
                for (int b = 0; b < 7; ++b) M[a][b] = 0.0;
#pragma unroll
            for (int a = 0; a < KG; ++a) {
#pragma unroll
                for (int b = 0; b < KG; ++b) M[a][b] = m[a] * Q[a][b] * m[b];
                M[a][a] += 1.0 - m[a];
                M[a][KG] = m[a];
                M[KG][a] = m[a];
                M[a][6] = -m[a] * p[a];
            }
            M[KG][6] = 1.0;
#pragma unroll
            for (int col = 0; col < 6; ++col) {
                const double dinv = 1.0 / M[col][col];
#pragma unroll
                for (int rr = 0; rr < 6; ++rr) {
                    if (rr > col) {
                        const double f = M[rr][col] * dinv;
#pragma unroll
                        for (int c = 0; c < 7; ++c)
                            if (c >= col) M[rr][c] -= f * M[col][c];
                    }
                }
            }
            double sol[6];
#pragma unroll
            for (int rr = 5; rr >= 0; --rr) {
                double s = M[rr][6];
#pragma unroll
                for (int c = 0; c < 6; ++c)
                    if (c > rr) s -= M[rr][c] * sol[c];
                sol[rr] = s / M[rr][rr];
            }
#pragma unroll
            for (int k = 0; k < KG; ++k) beta[k] = sol[k] * m[k];
            double o = 0.0;
#pragma unroll
            for (int a = 0; a < KG; ++a) {
                double qb = 0.0;
#pragma unroll
                for (int b = 0; b < KG; ++b) qb += Q[a][b] * beta[b];
                o += 0.5 * beta[a] * qb + p[a] * beta[a];
            }
            bool feas = true;
#pragma unroll
            for (int k = 0; k < KG; ++k) if (!(beta[k] >= -1e-7)) feas = false;
            obj = feas ? o : INFINITY;
        }

        double bobj = obj;
        int blane = valid ? mask : 9999;
        for (int off = 32; off > 0; off >>= 1) {
            const double o2 = __shfl_down(bobj, off, 64);
            const int l2 = __shfl_down(blane, off, 64);
            if (o2 < bobj || (o2 == bobj && l2 < blane)) { bobj = o2; blane = l2; }
        }
        bobj = __shfl(bobj, 0, 64);
        blane = __shfl(blane, 0, 64);
        if (bobj > 1e300) blane = 1;

        if (mask == blane) {
            double o = 0.0;
#pragma unroll
            for (int k = 0; k < KG; ++k) o += eta[k] * beta[k];
            out[0] = (float)o;
        }
    }
}

// ---------------- launch ----------------
extern "C" void kernel_launch(void* const* d_in, const int* in_sizes, int n_in,
                              void* d_out, int out_size, void* d_ws, size_t ws_size,
                              hipStream_t stream) {
    const float* Xs = (const float*)d_in[0];
    const float* Xt = (const float*)d_in[1];
    float* out = (float*)d_out;

    char* ws = (char*)d_ws;
    double* sums = (double*)ws;                                 // 16 doubles (128 B)
    float*  ns = (float*)(ws + 256);                            // 2048 f32
    float*  nt = (float*)(ws + 256 + 8192);                     // 2048 f32
    float*  h  = (float*)(ws + 256 + 16384);                    // 5*1024 f32
    unsigned short* Xsb = (unsigned short*)(ws + 40960);            // 2 MB bf16
    unsigned short* Xtb = (unsigned short*)(ws + 40960 + 2097152);  // 2 MB bf16

    prep_kernel<<<256, 256, 0, stream>>>(Xs, Xt, Xsb, Xtb, ns, nt, h, sums);
    gram_kernel<<<dim3(32, 32, 3), 256, 0, stream>>>(Xsb, Xtb, ns, nt, sums);
    finalize_kernel<<<1, 256, 0, stream>>>(sums, h, out);
}